// Round 1
// baseline (341.765 us; speedup 1.0000x reference)
//
#include <hip/hip_runtime.h>

// TestEBCModel: jagged embedding gather + SUM pool (T=4,B=8192,L=50,VOCAB=100000,D=128)
// followed by 3 stacked Linear(D,D) with no activation.
// Key insight: the MLP is affine -> precompute M = W1^T W2^T W3^T and
// c = (b1 W2^T + b2) W3^T + b3, then fuse pooling + single matvec per row.

#define T_ 4
#define B_ 8192
#define L_ 50
#define VOCAB_ 100000
#define D_ 128
#define ROWS 16        // rows per block in fused kernel
#define PSTRIDE 20     // padded LDS stride for transposed pooled tile

// ws layout (floats): A1[16384] | c1[128] | M[16384] | c[128]  (~132 KB)
#define WS_A1 0
#define WS_C1 16384
#define WS_M  16512
#define WS_C  32896

// ---- stage 1: A1 = W1^T @ W2^T ; c1 = b1 @ W2^T + b2 ----
__global__ __launch_bounds__(128) void combine1(const float* __restrict__ W1,
                                                const float* __restrict__ W2,
                                                const float* __restrict__ b1,
                                                const float* __restrict__ b2,
                                                float* __restrict__ ws) {
  const int j = threadIdx.x;
  const int i = blockIdx.x;
  if (i < D_) {
    float acc = 0.f;
    for (int k = 0; k < D_; ++k)
      acc += W1[k * D_ + i] * W2[j * D_ + k];   // A1[i][j] = sum_k W1[k][i] W2[j][k]
    ws[WS_A1 + i * D_ + j] = acc;
  } else {
    float acc = b2[j];
    for (int k = 0; k < D_; ++k)
      acc += b1[k] * W2[j * D_ + k];            // c1[j]
    ws[WS_C1 + j] = acc;
  }
}

// ---- stage 2: M = A1 @ W3^T ; c = c1 @ W3^T + b3 ----
__global__ __launch_bounds__(128) void combine2(const float* __restrict__ W3,
                                                const float* __restrict__ b3,
                                                const float* __restrict__ ws_in,
                                                float* __restrict__ ws) {
  const int j = threadIdx.x;
  const int i = blockIdx.x;
  if (i < D_) {
    float acc = 0.f;
    for (int k = 0; k < D_; ++k)
      acc += ws_in[WS_A1 + i * D_ + k] * W3[j * D_ + k];  // M[i][j]
    ws[WS_M + i * D_ + j] = acc;
  } else {
    float acc = b3[j];
    for (int k = 0; k < D_; ++k)
      acc += ws_in[WS_C1 + k] * W3[j * D_ + k];           // c[j]
    ws[WS_C + j] = acc;
  }
}

// ---- fused: pool 16 rows, then out[g][j] = c[j] + sum_i pooled[g][i]*M[i][j] ----
__global__ __launch_bounds__(256) void fused(const int* __restrict__ indices,
                                             const int* __restrict__ lengths,
                                             const float* __restrict__ tables,
                                             const float* __restrict__ ws,
                                             float* __restrict__ out) {
  __shared__ __align__(16) float pooledT[D_][PSTRIDE];  // [i][r], stride 20 keeps float4 16B-aligned
  __shared__ int   idx_sh[ROWS][L_];
  __shared__ float c_sh[D_];
  __shared__ int   len_sh[ROWS];

  const int tid = threadIdx.x;
  const int g0  = blockIdx.x * ROWS;

  // stage indices / lengths / bias
  for (int k = tid; k < ROWS * L_; k += 256)
    idx_sh[k / L_][k % L_] = indices[g0 * L_ + k];
  if (tid < D_)   c_sh[tid]  = ws[WS_C + tid];
  if (tid < ROWS) len_sh[tid] = lengths[g0 + tid];
  __syncthreads();

  const int d  = tid & (D_ - 1);
  const int rh = tid >> 7;                // 0 or 1; wave-uniform

  // phase 1: pooling — 128 threads per row, coalesced 512B row gathers, 4 in flight
  for (int rp = 0; rp < ROWS / 2; ++rp) {
    const int r = rp * 2 + rh;
    const int g = g0 + r;
    const int t = g >> 13;                // g / B_
    const float* tab = tables + (size_t)t * VOCAB_ * D_ + d;
    const int len = len_sh[r];
    float acc = 0.f;
    int l = 0;
    for (; l + 3 < len; l += 4) {
      const int i0 = idx_sh[r][l + 0];
      const int i1 = idx_sh[r][l + 1];
      const int i2 = idx_sh[r][l + 2];
      const int i3 = idx_sh[r][l + 3];
      const float v0 = tab[i0 * D_];
      const float v1 = tab[i1 * D_];
      const float v2 = tab[i2 * D_];
      const float v3 = tab[i3 * D_];
      acc += v0; acc += v1; acc += v2; acc += v3;
    }
    for (; l < len; ++l) acc += tab[idx_sh[r][l] * D_];
    pooledT[d][r] = acc;
  }
  __syncthreads();

  // phase 2: matvec with precomposed M — per i: 1 coalesced M load (wave reads 256B),
  // 2 broadcast ds_read_b128 of pooled, 8 FMAs.
  const int j = d;
  const int rbase = rh * 8;
  const float* Mg = ws + WS_M;
  float acc[8];
#pragma unroll
  for (int r = 0; r < 8; ++r) acc[r] = c_sh[j];
#pragma unroll 4
  for (int i = 0; i < D_; ++i) {
    const float m = Mg[i * D_ + j];
    const float4 p0 = *(const float4*)&pooledT[i][rbase];
    const float4 p1 = *(const float4*)&pooledT[i][rbase + 4];
    acc[0] += p0.x * m; acc[1] += p0.y * m; acc[2] += p0.z * m; acc[3] += p0.w * m;
    acc[4] += p1.x * m; acc[5] += p1.y * m; acc[6] += p1.z * m; acc[7] += p1.w * m;
  }
#pragma unroll
  for (int r = 0; r < 8; ++r)
    out[(size_t)(g0 + rbase + r) * D_ + j] = acc[r];
}

extern "C" void kernel_launch(void* const* d_in, const int* in_sizes, int n_in,
                              void* d_out, int out_size, void* d_ws, size_t ws_size,
                              hipStream_t stream) {
  const int*   indices = (const int*)d_in[0];
  const int*   lengths = (const int*)d_in[1];
  const float* tables  = (const float*)d_in[2];
  const float* W1      = (const float*)d_in[3];
  const float* b1      = (const float*)d_in[4];
  const float* W2      = (const float*)d_in[5];
  const float* b2      = (const float*)d_in[6];
  const float* W3      = (const float*)d_in[7];
  const float* b3      = (const float*)d_in[8];
  float*       out     = (float*)d_out;
  float*       ws      = (float*)d_ws;

  combine1<<<D_ + 1, D_, 0, stream>>>(W1, W2, b1, b2, ws);
  combine2<<<D_ + 1, D_, 0, stream>>>(W3, b3, ws, ws);
  fused<<<(T_ * B_) / ROWS, 256, 0, stream>>>(indices, lengths, tables, ws, out);
}